// Round 2
// baseline (2806.399 us; speedup 1.0000x reference)
//
#include <hip/hip_runtime.h>

typedef __attribute__((ext_vector_type(8))) short bf16x8;
typedef __attribute__((ext_vector_type(4))) float f32x4;
typedef unsigned short ushort_t;
typedef unsigned int uint32;

#define DEVI __device__ __forceinline__

static constexpr int Bn = 128, Sn = 256, In = 512, Hn = 512;
static constexpr int G3 = 3 * Hn;                 // 1536
static constexpr int GBLK = 32;                   // scan blocks (each owns 16 h-cols)

// ws layout (bytes)
static constexpr size_t GI_OFF    = 0;                              // bf16 [B*S][1536]
static constexpr size_t GI_BYTES  = (size_t)Bn * Sn * G3 * 2;       // 100,663,296
static constexpr size_t WIH_OFF   = GI_OFF + GI_BYTES;              // bf16 [1536][512]
static constexpr size_t WIH_BYTES = (size_t)G3 * In * 2;            // 1,572,864
static constexpr size_t HBUF_OFF  = WIH_OFF + WIH_BYTES;            // bf16 [2][B][H]
static constexpr size_t HBUF_BYTES= (size_t)2 * Bn * Hn * 2;        // 262,144
static constexpr size_t BAR_OFF   = HBUF_OFF + HBUF_BYTES;          // barrier counter

DEVI ushort_t f2bf(float f) {
  uint32 u = __builtin_bit_cast(uint32, f);
  u += 0x7FFFu + ((u >> 16) & 1u);
  return (ushort_t)(u >> 16);
}
DEVI float bf2f(ushort_t h) {
  uint32 u = ((uint32)h) << 16;
  return __builtin_bit_cast(float, u);
}
DEVI float sigmoid_f(float x) { return 1.0f / (1.0f + __expf(-x)); }
DEVI float tanh_f(float x)    { return 2.0f / (1.0f + __expf(-2.0f * x)) - 1.0f; }

// Device-scope barrier: monotone counter in ws (memset to 0 each launch).
// __threadfence() = agent-scope fence -> write back dirty XCD L2 + invalidate
// stale lines so cross-XCD h exchange is coherent (Guideline 16).
// WATCHDOG: bounded spin (~27ms) so a deadlock degrades to a wrong answer
// instead of wedging the GPU/container.
DEVI void gbar(uint32* bar, uint32 target) {
  __syncthreads();
  if (threadIdx.x == 0) {
    __threadfence();   // release
    __hip_atomic_fetch_add(bar, 1u, __ATOMIC_RELAXED, __HIP_MEMORY_SCOPE_AGENT);
    for (int spin = 0; spin < 1000000; ++spin) {
      if (__hip_atomic_load(bar, __ATOMIC_RELAXED, __HIP_MEMORY_SCOPE_AGENT) >= target)
        break;
      __builtin_amdgcn_s_sleep(1);
    }
    __threadfence();   // acquire
  }
  __syncthreads();
}

// --- kernel 0: convert W_ih f32 -> bf16 ---------------------------------
__global__ void k_cvt_wih(const float* __restrict__ wih, ushort_t* __restrict__ out) {
  int i = blockIdx.x * blockDim.x + threadIdx.x;   // float4 index, exact cover
  const float4 v = ((const float4*)wih)[i];
  ushort4 o;
  o.x = f2bf(v.x); o.y = f2bf(v.y); o.z = f2bf(v.z); o.w = f2bf(v.w);
  ((ushort4*)out)[i] = o;
}

// --- kernel 1: gi = x @ W_ih^T + b_ih  (bf16 out) -----------------------
// A-panel-resident: block owns 128 rows of x, stages them once as bf16 into
// 130KB dynamic LDS (padded stride 520 -> 2-way bank alias = free), then
// sweeps all 12 n-tiles reading W_ih bf16 fragments straight from L2.
__launch_bounds__(512)
__global__ void k_gi(const float* __restrict__ x, const ushort_t* __restrict__ wihb,
                     const float* __restrict__ b_ih, ushort_t* __restrict__ gi) {
  extern __shared__ ushort_t apan[];   // [128][520] bf16
  const int tid = threadIdx.x;
  const int bm  = blockIdx.x;          // rows [bm*128, +128)
#pragma unroll
  for (int it = 0; it < 32; ++it) {
    int fidx = it * 512 + tid;               // float4 index in [128][128]
    int row = fidx >> 7, c4 = fidx & 127;
    const float4 v = *(const float4*)(x + ((size_t)(bm * 128 + row) << 9) + (c4 << 2));
    ushort4 o;
    o.x = f2bf(v.x); o.y = f2bf(v.y); o.z = f2bf(v.z); o.w = f2bf(v.w);
    *(ushort4*)(&apan[row * 520 + (c4 << 2)]) = o;
  }
  __syncthreads();
  const int lane = tid & 63, wid = tid >> 6;
  const int l15 = lane & 15, hi = lane >> 4;
  const int arow = wid * 16 + l15;
  for (int nt = 0; nt < 12; ++nt) {
    const int n0 = nt * 128;
    f32x4 acc[8] = {};
#pragma unroll
    for (int ks = 0; ks < 16; ++ks) {
      bf16x8 a = *(const bf16x8*)(&apan[arow * 520 + ks * 32 + hi * 8]);
#pragma unroll
      for (int j = 0; j < 8; ++j) {
        const ushort_t* wp = wihb + ((size_t)(n0 + j * 16 + l15) << 9) + ks * 32 + hi * 8;
        bf16x8 b = *(const bf16x8*)wp;
        acc[j] = __builtin_amdgcn_mfma_f32_16x16x32_bf16(a, b, acc[j], 0, 0, 0);
      }
    }
#pragma unroll
    for (int j = 0; j < 8; ++j) {
      const int n = n0 + j * 16 + l15;
      const float bias = b_ih[n];
#pragma unroll
      for (int r = 0; r < 4; ++r) {
        int m = bm * 128 + wid * 16 + hi * 4 + r;   // D row = 4*(lane>>4)+reg
        gi[(size_t)m * 1536 + n] = f2bf(acc[j][r] + bias);
      }
    }
  }
}

// --- kernel 2: persistent masked-GRU scan -------------------------------
// 32 blocks x 512 threads. Block b owns h-cols [16b,16b+16) and the matching
// 48 W_hh rows (r/z/n) in LDS bf16 (padded stride 520). Per step: 8 waves each
// compute one 16-batch M-tile of gh[128][48] via MFMA reading the shared bf16
// h-state from global (double-buffered), then apply gates locally; one
// device barrier per step.
__launch_bounds__(512)
__global__ void k_scan(const float* __restrict__ hx, const float* __restrict__ mask,
                       const float* __restrict__ whh, const float* __restrict__ bhh,
                       const ushort_t* __restrict__ gi, ushort_t* __restrict__ hbuf,
                       uint32* __restrict__ bar, float* __restrict__ out) {
  __shared__ ushort_t Wl[48 * 520];   // 49,920 B
  __shared__ float hown[128 * 16];    //  8,192 B  (own f32 h columns)
  const int tid = threadIdx.x;
  const int c0 = blockIdx.x * 16;

  // stage W_hh slice (rows g*512 + c0 + j, g=0..2, j=0..15) as bf16
  for (int r = 0; r < 48; ++r) {
    int g = r >> 4, j = r & 15;
    Wl[r * 520 + tid] = f2bf(whh[(size_t)(g * 512 + c0 + j) * 512 + tid]);
  }
  // init h state: h0 = hx * mask[:,0]
  for (int i = tid; i < 2048; i += 512) {
    int b = i >> 4, j = i & 15;
    float v = hx[b * 512 + c0 + j] * mask[b * 256];
    hown[b * 16 + j] = v;
    hbuf[b * 512 + c0 + j] = f2bf(v);
  }
  uint32 tgt = GBLK;
  gbar(bar, tgt);

  const int lane = tid & 63, wid = tid >> 6;
  const int l15 = lane & 15, hi = lane >> 4;
  const float bhh_r = bhh[c0 + l15];
  const float bhh_z = bhh[512 + c0 + l15];
  const float bhh_n = bhh[1024 + c0 + l15];
  const int arow = wid * 16 + l15;
  int p = 0;

  for (int t = 0; t < 256; ++t) {
    // prefetch gi (bf16, streamed from HBM) + next-step mask; independent of h
    float giv0[4], giv1[4], giv2[4], mk[4];
#pragma unroll
    for (int r = 0; r < 4; ++r) {
      int b = wid * 16 + hi * 4 + r;
      size_t gb = (size_t)(b * 256 + t) * 1536 + c0 + l15;
      giv0[r] = bf2f(gi[gb]);
      giv1[r] = bf2f(gi[gb + 512]);
      giv2[r] = bf2f(gi[gb + 1024]);
      mk[r] = (t < 255) ? mask[b * 256 + t + 1] : 0.0f;
    }

    const ushort_t* hb = hbuf + (size_t)p * (128 * 512);
    f32x4 acc[3] = {};
#pragma unroll
    for (int ks = 0; ks < 16; ++ks) {
      bf16x8 a = *(const bf16x8*)(hb + arow * 512 + ks * 32 + hi * 8);
#pragma unroll
      for (int g = 0; g < 3; ++g) {
        bf16x8 w = *(const bf16x8*)(&Wl[(g * 16 + l15) * 520 + ks * 32 + hi * 8]);
        acc[g] = __builtin_amdgcn_mfma_f32_16x16x32_bf16(a, w, acc[g], 0, 0, 0);
      }
    }

    ushort_t* hw = hbuf + (size_t)(p ^ 1) * (128 * 512);
#pragma unroll
    for (int r = 0; r < 4; ++r) {
      int b = wid * 16 + hi * 4 + r;
      float rg = sigmoid_f(giv0[r] + acc[0][r] + bhh_r);
      float zg = sigmoid_f(giv1[r] + acc[1][r] + bhh_z);
      float ng = tanh_f(giv2[r] + rg * (acc[2][r] + bhh_n));
      float hin = hown[b * 16 + l15];
      float hn = (1.0f - zg) * ng + zg * hin;
      out[(size_t)(b * 256 + t) * 512 + c0 + l15] = hn;          // hs[b][t][:]
      if (t == 255) {
        out[(size_t)(128 * 256) * 512 + b * 512 + c0 + l15] = hn; // h_last
      } else {
        float hm = hn * mk[r];
        hown[b * 16 + l15] = hm;
        hw[b * 512 + c0 + l15] = f2bf(hm);
      }
    }
    if (t < 255) { tgt += GBLK; gbar(bar, tgt); p ^= 1; }
  }
}

extern "C" void kernel_launch(void* const* d_in, const int* in_sizes, int n_in,
                              void* d_out, int out_size, void* d_ws, size_t ws_size,
                              hipStream_t stream) {
  (void)in_sizes; (void)n_in; (void)out_size; (void)ws_size;
  const float* x    = (const float*)d_in[0];
  const float* hx   = (const float*)d_in[1];
  const float* mask = (const float*)d_in[2];
  const float* Wih  = (const float*)d_in[3];
  const float* Whh  = (const float*)d_in[4];
  const float* bih  = (const float*)d_in[5];
  const float* bhh  = (const float*)d_in[6];
  float* out = (float*)d_out;
  char* ws = (char*)d_ws;
  ushort_t* gi   = (ushort_t*)(ws + GI_OFF);
  ushort_t* wihb = (ushort_t*)(ws + WIH_OFF);
  ushort_t* hbuf = (ushort_t*)(ws + HBUF_OFF);
  uint32*   bar  = (uint32*)(ws + BAR_OFF);

  hipMemsetAsync(bar, 0, 256, stream);                      // reset barrier each call
  k_cvt_wih<<<768, 256, 0, stream>>>(Wih, wihb);            // 786,432 f32 -> bf16
  k_gi<<<256, 512, 128 * 520 * 2, stream>>>(x, wihb, bih, gi);
  k_scan<<<GBLK, 512, 0, stream>>>(hx, mask, Whh, bhh, gi, hbuf, bar, out);
}